// Round 1
// baseline (179.108 us; speedup 1.0000x reference)
//
#include <hip/hip_runtime.h>

// Problem constants: H=W=32, HW=1024, C=512, 2C=1024, sigma=1.5 -> 2*v^2=4.5

__device__ __forceinline__ float block_reduce_256(float v, float* sm4) {
  #pragma unroll
  for (int off = 32; off >= 1; off >>= 1) v += __shfl_down(v, off);
  __syncthreads();                      // protect sm4 reuse across calls
  if ((threadIdx.x & 63) == 0) sm4[threadIdx.x >> 6] = v;
  __syncthreads();
  return sm4[0] + sm4[1] + sm4[2] + sm4[3];
}

// --- K0: normalized separable 1D gaussian weights gn[32][32] ---
__global__ void k_gn(float* __restrict__ gn) {
  int a = threadIdx.x;  // 32 threads
  float e[32];
  float s = 0.0f;
  #pragma unroll
  for (int b = 0; b < 32; b++) {
    float d = (float)(a - b);
    float v = __expf(d * d * (-1.0f / 4.5f));
    e[b] = v; s += v;
  }
  float inv = 1.0f / s;
  #pragma unroll
  for (int b = 0; b < 32; b++) gn[a * 32 + b] = e[b] * inv;
}

// --- K1: per-channel spatial mean of x ---
__global__ void k_mean(const float* __restrict__ x, float* __restrict__ smean) {
  __shared__ float sm4[4];
  int c = blockIdx.x;
  const float* row = x + c * 1024;
  float s = 0.0f;
  for (int i = threadIdx.x; i < 1024; i += 256) s += row[i];
  float t = block_reduce_256(s, sm4);
  if (threadIdx.x == 0) smean[c] = t * (1.0f / 1024.0f);
}

// --- K2: SE fc1(relu) + fc2(sigmoid) -> s2[512] ---
__global__ void k_se(const float* __restrict__ smean, const float* __restrict__ w1,
                     const float* __restrict__ w2, float* __restrict__ s2out) {
  __shared__ float sm[512];
  __shared__ float s1[32];
  int tid = threadIdx.x;
  for (int i = tid; i < 512; i += 256) sm[i] = smean[i];
  __syncthreads();
  int j = tid >> 3, l8 = tid & 7;       // 32 outputs x 8 threads
  float a = 0.0f;
  for (int cc = l8; cc < 512; cc += 8) a += sm[cc] * w1[j * 512 + cc];
  a += __shfl_down(a, 4, 8);
  a += __shfl_down(a, 2, 8);
  a += __shfl_down(a, 1, 8);
  if (l8 == 0) s1[j] = fmaxf(a, 0.0f);
  __syncthreads();
  for (int cc = tid; cc < 512; cc += 256) {
    float b = 0.0f;
    #pragma unroll
    for (int jj = 0; jj < 32; jj++) b += s1[jj] * w2[cc * 32 + jj];
    s2out[cc] = 1.0f / (1.0f + __expf(-b));
  }
}

// --- K3: out32 = x * s2[c]; also transposed copies out32T, sigT (LDS transpose) ---
__global__ void k_apply(const float* __restrict__ x, const float* __restrict__ s2,
                        float* __restrict__ out32, float* __restrict__ out32T,
                        float* __restrict__ sigT) {
  __shared__ float tile[32][33];
  __shared__ float sc[32];
  int c0 = blockIdx.y * 32, hw0 = blockIdx.x * 32;
  int tx = threadIdx.x & 31, ty = threadIdx.x >> 5;  // ty 0..7
  if (threadIdx.x < 32) sc[threadIdx.x] = s2[c0 + threadIdx.x];
  __syncthreads();
  #pragma unroll
  for (int r = 0; r < 4; r++) {
    int c = ty + 8 * r;
    float v = x[(c0 + c) * 1024 + hw0 + tx] * sc[c];
    out32[(c0 + c) * 1024 + hw0 + tx] = v;
    tile[c][tx] = v;
  }
  __syncthreads();
  #pragma unroll
  for (int r = 0; r < 4; r++) {
    int hw = ty + 8 * r;
    float v = tile[tx][hw];
    out32T[(hw0 + hw) * 512 + c0 + tx] = v;
    sigT[(hw0 + hw) * 512 + c0 + tx] = 1.0f / (1.0f + __expf(-v));
  }
}

// --- K4: gaussian pass 1 (over y): t[k][c][x] = sum_y gn[k,y]*out32[c,x,y] ---
__global__ void k_gauss1(const float* __restrict__ out32, const float* __restrict__ gn,
                         float* __restrict__ t) {
  __shared__ float row[32 * 33];  // padded [x][y]
  __shared__ float g[1024];
  int c = blockIdx.x;
  for (int idx = threadIdx.x; idx < 1024; idx += 256) {
    int xx = idx >> 5, yy = idx & 31;
    row[xx * 33 + yy] = out32[c * 1024 + idx];
    g[idx] = gn[idx];
  }
  __syncthreads();
  for (int idx = threadIdx.x; idx < 1024; idx += 256) {
    int k = idx >> 5, xx = idx & 31;
    float s = 0.0f;
    #pragma unroll
    for (int y = 0; y < 32; y++) s += g[k * 32 + y] * row[xx * 33 + y];
    t[(k * 512 + c) * 32 + xx] = s;
  }
}

// --- K5: gaussian pass 2 (over x): cat[p*512+c] = sum_x gn[i,x]*t[k][c][x] ---
__global__ void k_gauss2(const float* __restrict__ t, const float* __restrict__ gn,
                         float* __restrict__ catg) {
  int gid = blockIdx.x * 256 + threadIdx.x;  // == p*512 + c
  int c = gid & 511, p = gid >> 9;
  int i = p >> 5, k = p & 31;
  const float4* tp = (const float4*)(t + (k * 512 + c) * 32);
  const float4* gp = (const float4*)(gn + i * 32);
  float s = 0.0f;
  #pragma unroll
  for (int q = 0; q < 8; q++) {
    float4 tv = tp[q], gv = gp[q];
    s += tv.x * gv.x + tv.y * gv.y + tv.z * gv.z + tv.w * gv.w;
  }
  catg[gid] = s;
}

// --- K6: CSA per location p: 9 channel-dots -> softmax -> weighted patch sum ---
__global__ void k_csa(const float* __restrict__ sigT, const float* __restrict__ out32T,
                      float* __restrict__ ocsa) {
  int p = blockIdx.x;
  int h = p >> 5, w = p & 31;
  __shared__ float center[512];
  __shared__ float red[4][9];
  __shared__ float att_s[9];
  int tid = threadIdx.x;
  for (int c = tid; c < 512; c += 256) center[c] = sigT[p * 512 + c];
  __syncthreads();
  float sc[9];
  int qoff[9];
  #pragma unroll
  for (int dd = 0; dd < 9; dd++) {
    int hh = h + dd / 3 - 1, ww = w + (dd % 3) - 1;
    bool v = (hh >= 0) && (hh < 32) && (ww >= 0) && (ww < 32);
    qoff[dd] = v ? (hh * 32 + ww) * 512 : -1;
    float a = 0.0f;
    if (v) {
      const float* nb = sigT + qoff[dd];
      for (int c = tid; c < 512; c += 256) a += center[c] * nb[c];
    }
    #pragma unroll
    for (int off = 32; off >= 1; off >>= 1) a += __shfl_down(a, off);
    sc[dd] = a;
  }
  if ((tid & 63) == 0) {
    int wv = tid >> 6;
    #pragma unroll
    for (int dd = 0; dd < 9; dd++) red[wv][dd] = sc[dd];
  }
  __syncthreads();
  if (tid == 0) {
    float s[9];
    float mx = -1e30f;
    #pragma unroll
    for (int dd = 0; dd < 9; dd++) {
      s[dd] = (red[0][dd] + red[1][dd] + red[2][dd] + red[3][dd]) * (1.0f / 512.0f);
      mx = fmaxf(mx, s[dd]);
    }
    float tot = 0.0f;
    #pragma unroll
    for (int dd = 0; dd < 9; dd++) { s[dd] = __expf(s[dd] - mx); tot += s[dd]; }
    float inv = 1.0f / tot;
    #pragma unroll
    for (int dd = 0; dd < 9; dd++) att_s[dd] = s[dd] * inv;
  }
  __syncthreads();
  float att[9];
  #pragma unroll
  for (int dd = 0; dd < 9; dd++) att[dd] = att_s[dd];
  for (int c = tid; c < 512; c += 256) {
    float o = 0.0f;
    #pragma unroll
    for (int dd = 0; dd < 9; dd++) {
      if (qoff[dd] >= 0) o += att[dd] * out32T[qoff[dd] + c];
    }
    ocsa[p * 512 + c] = o;
  }
}

// --- K7: fp32 GEMM y[512][1024] = w_down[512][1024] * cat[1024][1024] ---
__global__ void k_gemm(const float* __restrict__ A, const float* __restrict__ B,
                       float* __restrict__ Cm) {
  __shared__ float As[32][33];
  __shared__ float Bs[32][33];
  int tx = threadIdx.x & 31;
  int ty = threadIdx.x >> 5;  // 0..7
  int bm = blockIdx.y * 32;
  int bn = blockIdx.x * 32;
  float acc0 = 0, acc1 = 0, acc2 = 0, acc3 = 0;
  for (int k0 = 0; k0 < 1024; k0 += 32) {
    #pragma unroll
    for (int r = 0; r < 4; r++) {
      As[ty + 8 * r][tx] = A[(bm + ty + 8 * r) * 1024 + k0 + tx];
      Bs[ty + 8 * r][tx] = B[(k0 + ty + 8 * r) * 1024 + bn + tx];
    }
    __syncthreads();
    #pragma unroll
    for (int k = 0; k < 32; k++) {
      float b = Bs[k][tx];
      acc0 += As[ty][k] * b;
      acc1 += As[ty + 8][k] * b;
      acc2 += As[ty + 16][k] * b;
      acc3 += As[ty + 24][k] * b;
    }
    __syncthreads();
  }
  Cm[(bm + ty) * 1024 + bn + tx] = acc0;
  Cm[(bm + ty + 8) * 1024 + bn + tx] = acc1;
  Cm[(bm + ty + 16) * 1024 + bn + tx] = acc2;
  Cm[(bm + ty + 24) * 1024 + bn + tx] = acc3;
}

// --- K8: instance norm (biased var) + LeakyReLU(0.2) ---
__global__ void k_inorm(const float* __restrict__ y, float* __restrict__ out) {
  __shared__ float sm4[4];
  int o = blockIdx.x;
  const float* row = y + o * 1024;
  float s = 0.0f, q = 0.0f;
  for (int i = threadIdx.x; i < 1024; i += 256) { float v = row[i]; s += v; q += v * v; }
  float ts = block_reduce_256(s, sm4);
  float tq = block_reduce_256(q, sm4);
  float mean = ts * (1.0f / 1024.0f);
  float var = tq * (1.0f / 1024.0f) - mean * mean;
  float inv = rsqrtf(var + 1e-5f);
  for (int i = threadIdx.x; i < 1024; i += 256) {
    float v = (row[i] - mean) * inv;
    out[o * 1024 + i] = v >= 0.0f ? v : 0.2f * v;
  }
}

extern "C" void kernel_launch(void* const* d_in, const int* in_sizes, int n_in,
                              void* d_out, int out_size, void* d_ws, size_t ws_size,
                              hipStream_t stream) {
  const float* x      = (const float*)d_in[0];  // (1,512,32,32)
  const float* w_se1  = (const float*)d_in[1];  // (32,512)
  const float* w_se2  = (const float*)d_in[2];  // (512,32)
  const float* w_down = (const float*)d_in[3];  // (512,1024,1,1)
  float* out = (float*)d_out;                   // (1,512,32,32)

  float* ws = (float*)d_ws;
  float* gn     = ws;                  // 1024
  float* smean  = ws + 1024;           // 512
  float* s2     = ws + 1536;           // 512
  float* out32  = ws + 2048;           // 524288   (c-major)
  float* out32T = out32 + 524288;      // 524288   (hw-major)
  float* sigT   = out32T + 524288;     // 524288   (hw-major)
  float* tbuf   = sigT + 524288;       // 524288   t[k][c][x]
  float* cat    = tbuf + 524288;       // 1048576  GEMM B matrix (gus | csa)
  float* ybuf   = cat + 1048576;       // 524288

  k_gn<<<1, 32, 0, stream>>>(gn);
  k_mean<<<512, 256, 0, stream>>>(x, smean);
  k_se<<<1, 256, 0, stream>>>(smean, w_se1, w_se2, s2);
  k_apply<<<dim3(32, 16), 256, 0, stream>>>(x, s2, out32, out32T, sigT);
  k_gauss1<<<512, 256, 0, stream>>>(out32, gn, tbuf);
  k_gauss2<<<2048, 256, 0, stream>>>(tbuf, gn, cat);                 // first half of cat
  k_csa<<<1024, 256, 0, stream>>>(sigT, out32T, cat + 524288);       // second half of cat
  k_gemm<<<dim3(32, 16), 256, 0, stream>>>(w_down, cat, ybuf);
  k_inorm<<<512, 256, 0, stream>>>(ybuf, out);
}

// Round 2
// 129.201 us; speedup vs baseline: 1.3863x; 1.3863x over previous
//
#include <hip/hip_runtime.h>

// Problem constants: H=W=32, HW=1024, C=512, 2C=1024, sigma=1.5 -> 2*v^2=4.5

__device__ __forceinline__ float block_reduce_256(float v, float* sm4) {
  #pragma unroll
  for (int off = 32; off >= 1; off >>= 1) v += __shfl_down(v, off);
  __syncthreads();                      // protect sm4 reuse across calls
  if ((threadIdx.x & 63) == 0) sm4[threadIdx.x >> 6] = v;
  __syncthreads();
  return sm4[0] + sm4[1] + sm4[2] + sm4[3];
}

// --- K1: per-channel spatial mean of x (blocks 0..511) + gaussian weights (block 512) ---
__global__ void k_mean_gn(const float* __restrict__ x, float* __restrict__ smean,
                          float* __restrict__ gn) {
  if (blockIdx.x == 512) {
    int tid = threadIdx.x;
    int a = tid >> 3;            // 0..31 row
    int b0 = (tid & 7) * 4;      // 4 cols per thread
    float e[4];
    float s = 0.0f;
    #pragma unroll
    for (int q = 0; q < 4; q++) {
      float d = (float)(a - (b0 + q));
      e[q] = __expf(d * d * (-1.0f / 4.5f));
      s += e[q];
    }
    s += __shfl_xor(s, 1, 8);
    s += __shfl_xor(s, 2, 8);
    s += __shfl_xor(s, 4, 8);
    float inv = 1.0f / s;
    #pragma unroll
    for (int q = 0; q < 4; q++) gn[a * 32 + b0 + q] = e[q] * inv;
    return;
  }
  __shared__ float sm4[4];
  int c = blockIdx.x;
  const float* row = x + c * 1024;
  float s = 0.0f;
  for (int i = threadIdx.x; i < 1024; i += 256) s += row[i];
  float t = block_reduce_256(s, sm4);
  if (threadIdx.x == 0) smean[c] = t * (1.0f / 1024.0f);
}

// --- K3: SE (fc1+relu+fc2+sigmoid, redundant per block) + scale + transposes ---
__global__ void k_apply(const float* __restrict__ x, const float* __restrict__ smean,
                        const float* __restrict__ w1, const float* __restrict__ w2,
                        float* __restrict__ out32, float* __restrict__ out32T,
                        float* __restrict__ sigT) {
  __shared__ float sm[512];
  __shared__ float s1[32];
  __shared__ float sc[32];
  __shared__ float tile[32][33];
  int tid = threadIdx.x;
  for (int i = tid; i < 512; i += 256) sm[i] = smean[i];
  __syncthreads();
  // fc1: 32 outputs x 8 threads
  int j = tid >> 3, l8 = tid & 7;
  float a = 0.0f;
  for (int cc = l8; cc < 512; cc += 8) a += sm[cc] * w1[j * 512 + cc];
  a += __shfl_down(a, 4, 8);
  a += __shfl_down(a, 2, 8);
  a += __shfl_down(a, 1, 8);
  if (l8 == 0) s1[j] = fmaxf(a, 0.0f);
  __syncthreads();
  int c0 = blockIdx.y * 32, hw0 = blockIdx.x * 32;
  if (tid < 32) {
    float b = 0.0f;
    #pragma unroll
    for (int jj = 0; jj < 32; jj++) b += s1[jj] * w2[(c0 + tid) * 32 + jj];
    sc[tid] = 1.0f / (1.0f + __expf(-b));
  }
  __syncthreads();
  int tx = tid & 31, ty = tid >> 5;  // ty 0..7
  #pragma unroll
  for (int r = 0; r < 4; r++) {
    int c = ty + 8 * r;
    float v = x[(c0 + c) * 1024 + hw0 + tx] * sc[c];
    out32[(c0 + c) * 1024 + hw0 + tx] = v;
    tile[c][tx] = v;
  }
  __syncthreads();
  #pragma unroll
  for (int r = 0; r < 4; r++) {
    int hw = ty + 8 * r;
    float v = tile[tx][hw];
    out32T[(hw0 + hw) * 512 + c0 + tx] = v;
    sigT[(hw0 + hw) * 512 + c0 + tx] = 1.0f / (1.0f + __expf(-v));
  }
}

// --- K4: gaussian pass 1 (over y): t[k][c][x] = sum_y gn[k,y]*out32[c,x,y] ---
__global__ void k_gauss1(const float* __restrict__ out32, const float* __restrict__ gn,
                         float* __restrict__ t) {
  __shared__ float row[32 * 33];  // padded [x][y]
  __shared__ float g[1024];
  int c = blockIdx.x;
  for (int idx = threadIdx.x; idx < 1024; idx += 256) {
    int xx = idx >> 5, yy = idx & 31;
    row[xx * 33 + yy] = out32[c * 1024 + idx];
    g[idx] = gn[idx];
  }
  __syncthreads();
  for (int idx = threadIdx.x; idx < 1024; idx += 256) {
    int k = idx >> 5, xx = idx & 31;
    float s = 0.0f;
    #pragma unroll
    for (int y = 0; y < 32; y++) s += g[k * 32 + y] * row[xx * 33 + y];
    t[(k * 512 + c) * 32 + xx] = s;
  }
}

// --- K5: gaussian pass 2 (over x): cat[p*512+c] = sum_x gn[i,x]*t[k][c][x] ---
__global__ void k_gauss2(const float* __restrict__ t, const float* __restrict__ gn,
                         float* __restrict__ catg) {
  int gid = blockIdx.x * 256 + threadIdx.x;  // == p*512 + c
  int c = gid & 511, p = gid >> 9;
  int i = p >> 5, k = p & 31;
  const float4* tp = (const float4*)(t + (k * 512 + c) * 32);
  const float4* gp = (const float4*)(gn + i * 32);
  float s = 0.0f;
  #pragma unroll
  for (int q = 0; q < 8; q++) {
    float4 tv = tp[q], gv = gp[q];
    s += tv.x * gv.x + tv.y * gv.y + tv.z * gv.z + tv.w * gv.w;
  }
  catg[gid] = s;
}

// --- K6: CSA per location p: 9 channel-dots -> softmax -> weighted patch sum ---
__global__ void k_csa(const float* __restrict__ sigT, const float* __restrict__ out32T,
                      float* __restrict__ ocsa) {
  int p = blockIdx.x;
  int h = p >> 5, w = p & 31;
  __shared__ float center[512];
  __shared__ float red[4][9];
  __shared__ float att_s[9];
  int tid = threadIdx.x;
  for (int c = tid; c < 512; c += 256) center[c] = sigT[p * 512 + c];
  __syncthreads();
  float sc[9];
  int qoff[9];
  #pragma unroll
  for (int dd = 0; dd < 9; dd++) {
    int hh = h + dd / 3 - 1, ww = w + (dd % 3) - 1;
    bool v = (hh >= 0) && (hh < 32) && (ww >= 0) && (ww < 32);
    qoff[dd] = v ? (hh * 32 + ww) * 512 : -1;
    float a = 0.0f;
    if (v) {
      const float* nb = sigT + qoff[dd];
      for (int c = tid; c < 512; c += 256) a += center[c] * nb[c];
    }
    #pragma unroll
    for (int off = 32; off >= 1; off >>= 1) a += __shfl_down(a, off);
    sc[dd] = a;
  }
  if ((tid & 63) == 0) {
    int wv = tid >> 6;
    #pragma unroll
    for (int dd = 0; dd < 9; dd++) red[wv][dd] = sc[dd];
  }
  __syncthreads();
  if (tid == 0) {
    float s[9];
    float mx = -1e30f;
    #pragma unroll
    for (int dd = 0; dd < 9; dd++) {
      s[dd] = (red[0][dd] + red[1][dd] + red[2][dd] + red[3][dd]) * (1.0f / 512.0f);
      mx = fmaxf(mx, s[dd]);
    }
    float tot = 0.0f;
    #pragma unroll
    for (int dd = 0; dd < 9; dd++) { s[dd] = __expf(s[dd] - mx); tot += s[dd]; }
    float inv = 1.0f / tot;
    #pragma unroll
    for (int dd = 0; dd < 9; dd++) att_s[dd] = s[dd] * inv;
  }
  __syncthreads();
  float att[9];
  #pragma unroll
  for (int dd = 0; dd < 9; dd++) att[dd] = att_s[dd];
  for (int c = tid; c < 512; c += 256) {
    float o = 0.0f;
    #pragma unroll
    for (int dd = 0; dd < 9; dd++) {
      if (qoff[dd] >= 0) o += att[dd] * out32T[qoff[dd] + c];
    }
    ocsa[p * 512 + c] = o;
  }
}

// --- K7: fp32 GEMM y[512][1024] = w_down[512][1024] * cat[1024][1024] ---
// 64x64 tile, 4x4 per thread, K-split 4 (blockIdx.z), partials summed in k_inorm.
__global__ void k_gemm(const float* __restrict__ A, const float* __restrict__ B,
                       float* __restrict__ Cp) {
  __shared__ __align__(16) float As[32][68];  // [k][m], stride 68: b128-aligned reads
  __shared__ __align__(16) float Bs[32][64];  // [k][n]
  int tid = threadIdx.x;
  int tx = tid & 15;        // n-quad
  int ty = tid >> 4;        // m-quad (0..15)
  int bn = blockIdx.x * 64;
  int bm = blockIdx.y * 64;
  int zK = blockIdx.z * 256;
  int a_m = tid >> 5;       // 0..7
  int a_k = tid & 31;
  int b_row = tid >> 4;     // 0..15
  int b_q = tid & 15;
  float acc[4][4] = {};
  for (int k0 = 0; k0 < 256; k0 += 32) {
    // A-tile transpose-staged: As[k][m] = A[(bm+m)*1024 + zK+k0+k]
    #pragma unroll
    for (int r = 0; r < 8; r++) {
      As[a_k][a_m + 8 * r] = A[(bm + a_m + 8 * r) * 1024 + zK + k0 + a_k];
    }
    // B-tile: Bs[k][n], float4 both sides
    #pragma unroll
    for (int r = 0; r < 2; r++) {
      float4 v = *(const float4*)&B[(zK + k0 + b_row + 16 * r) * 1024 + bn + b_q * 4];
      *(float4*)&Bs[b_row + 16 * r][b_q * 4] = v;
    }
    __syncthreads();
    #pragma unroll
    for (int k = 0; k < 32; k++) {
      float4 av = *(const float4*)&As[k][ty * 4];
      float4 bv = *(const float4*)&Bs[k][tx * 4];
      acc[0][0] += av.x * bv.x; acc[0][1] += av.x * bv.y; acc[0][2] += av.x * bv.z; acc[0][3] += av.x * bv.w;
      acc[1][0] += av.y * bv.x; acc[1][1] += av.y * bv.y; acc[1][2] += av.y * bv.z; acc[1][3] += av.y * bv.w;
      acc[2][0] += av.z * bv.x; acc[2][1] += av.z * bv.y; acc[2][2] += av.z * bv.z; acc[2][3] += av.z * bv.w;
      acc[3][0] += av.w * bv.x; acc[3][1] += av.w * bv.y; acc[3][2] += av.w * bv.z; acc[3][3] += av.w * bv.w;
    }
    __syncthreads();
  }
  float* Cz = Cp + blockIdx.z * 524288;
  #pragma unroll
  for (int i = 0; i < 4; i++) {
    float4 v = make_float4(acc[i][0], acc[i][1], acc[i][2], acc[i][3]);
    *(float4*)&Cz[(bm + ty * 4 + i) * 1024 + bn + tx * 4] = v;
  }
}

// --- K8: sum 4 K-split partials + instance norm (biased var) + LeakyReLU(0.2) ---
__global__ void k_inorm(const float* __restrict__ yp, float* __restrict__ out) {
  __shared__ float sm4[4];
  __shared__ float vrow[1024];
  int o = blockIdx.x;
  const float* r0 = yp + o * 1024;
  float s = 0.0f, q = 0.0f;
  for (int i = threadIdx.x; i < 1024; i += 256) {
    float v = r0[i] + r0[i + 524288] + r0[i + 2 * 524288] + r0[i + 3 * 524288];
    vrow[i] = v;
    s += v; q += v * v;
  }
  float ts = block_reduce_256(s, sm4);
  float tq = block_reduce_256(q, sm4);
  float mean = ts * (1.0f / 1024.0f);
  float var = tq * (1.0f / 1024.0f) - mean * mean;
  float inv = rsqrtf(var + 1e-5f);
  for (int i = threadIdx.x; i < 1024; i += 256) {
    float v = (vrow[i] - mean) * inv;
    out[o * 1024 + i] = v >= 0.0f ? v : 0.2f * v;
  }
}

extern "C" void kernel_launch(void* const* d_in, const int* in_sizes, int n_in,
                              void* d_out, int out_size, void* d_ws, size_t ws_size,
                              hipStream_t stream) {
  const float* x      = (const float*)d_in[0];  // (1,512,32,32)
  const float* w_se1  = (const float*)d_in[1];  // (32,512)
  const float* w_se2  = (const float*)d_in[2];  // (512,32)
  const float* w_down = (const float*)d_in[3];  // (512,1024,1,1)
  float* out = (float*)d_out;                   // (1,512,32,32)

  float* ws = (float*)d_ws;
  float* gn     = ws;                  // 1024
  float* smean  = ws + 1024;           // 512
  float* out32  = ws + 2048;           // 524288   (c-major)
  float* out32T = out32 + 524288;      // 524288   (hw-major)
  float* sigT   = out32T + 524288;     // 524288   (hw-major)
  float* tbuf   = sigT + 524288;       // 524288   t[k][c][x]
  float* cat    = tbuf + 524288;       // 1048576  GEMM B matrix (gus | csa)
  // ypart aliases out32..tbuf (all dead before k_gemm runs): 4 x 524288 floats
  float* ypart  = out32;

  k_mean_gn<<<513, 256, 0, stream>>>(x, smean, gn);
  k_apply<<<dim3(32, 16), 256, 0, stream>>>(x, smean, w_se1, w_se2, out32, out32T, sigT);
  k_gauss1<<<512, 256, 0, stream>>>(out32, gn, tbuf);
  k_gauss2<<<2048, 256, 0, stream>>>(tbuf, gn, cat);                 // first half of cat
  k_csa<<<1024, 256, 0, stream>>>(sigT, out32T, cat + 524288);       // second half of cat
  k_gemm<<<dim3(16, 8, 4), 256, 0, stream>>>(w_down, cat, ypart);
  k_inorm<<<512, 256, 0, stream>>>(ypart, out);
}

// Round 3
// 117.161 us; speedup vs baseline: 1.5287x; 1.1028x over previous
//
#include <hip/hip_runtime.h>

// Problem constants: H=W=32, HW=1024, C=512, 2C=1024, sigma=1.5 -> 2*v^2=4.5

__device__ __forceinline__ float block_reduce_256(float v, float* sm4) {
  #pragma unroll
  for (int off = 32; off >= 1; off >>= 1) v += __shfl_down(v, off);
  __syncthreads();                      // protect sm4 reuse across calls
  if ((threadIdx.x & 63) == 0) sm4[threadIdx.x >> 6] = v;
  __syncthreads();
  return sm4[0] + sm4[1] + sm4[2] + sm4[3];
}

// --- K1: per-channel spatial mean of x (blocks 0..511) + gaussian weights (block 512) ---
__global__ void k_mean_gn(const float* __restrict__ x, float* __restrict__ smean,
                          float* __restrict__ gn) {
  if (blockIdx.x == 512) {
    int tid = threadIdx.x;
    int a = tid >> 3;            // 0..31 row
    int b0 = (tid & 7) * 4;      // 4 cols per thread
    float e[4];
    float s = 0.0f;
    #pragma unroll
    for (int q = 0; q < 4; q++) {
      float d = (float)(a - (b0 + q));
      e[q] = __expf(d * d * (-1.0f / 4.5f));
      s += e[q];
    }
    s += __shfl_xor(s, 1, 8);
    s += __shfl_xor(s, 2, 8);
    s += __shfl_xor(s, 4, 8);
    float inv = 1.0f / s;
    #pragma unroll
    for (int q = 0; q < 4; q++) gn[a * 32 + b0 + q] = e[q] * inv;
    return;
  }
  __shared__ float sm4[4];
  int c = blockIdx.x;
  const float* row = x + c * 1024;
  float s = 0.0f;
  for (int i = threadIdx.x; i < 1024; i += 256) s += row[i];
  float t = block_reduce_256(s, sm4);
  if (threadIdx.x == 0) smean[c] = t * (1.0f / 1024.0f);
}

// --- K2: SE (fc1+relu+fc2+sigmoid, redundant per block) + scale + transposes ---
__global__ void k_apply(const float* __restrict__ x, const float* __restrict__ smean,
                        const float* __restrict__ w1, const float* __restrict__ w2,
                        float* __restrict__ out32, float* __restrict__ out32T,
                        float* __restrict__ sigT) {
  __shared__ float sm[512];
  __shared__ float s1[32];
  __shared__ float sc[32];
  __shared__ float tile[32][33];
  int tid = threadIdx.x;
  for (int i = tid; i < 512; i += 256) sm[i] = smean[i];
  __syncthreads();
  // fc1: 32 outputs x 8 threads
  int j = tid >> 3, l8 = tid & 7;
  float a = 0.0f;
  for (int cc = l8; cc < 512; cc += 8) a += sm[cc] * w1[j * 512 + cc];
  a += __shfl_down(a, 4, 8);
  a += __shfl_down(a, 2, 8);
  a += __shfl_down(a, 1, 8);
  if (l8 == 0) s1[j] = fmaxf(a, 0.0f);
  __syncthreads();
  int c0 = blockIdx.y * 32, hw0 = blockIdx.x * 32;
  if (tid < 32) {
    float b = 0.0f;
    #pragma unroll
    for (int jj = 0; jj < 32; jj++) b += s1[jj] * w2[(c0 + tid) * 32 + jj];
    sc[tid] = 1.0f / (1.0f + __expf(-b));
  }
  __syncthreads();
  int tx = tid & 31, ty = tid >> 5;  // ty 0..7
  #pragma unroll
  for (int r = 0; r < 4; r++) {
    int c = ty + 8 * r;
    float v = x[(c0 + c) * 1024 + hw0 + tx] * sc[c];
    out32[(c0 + c) * 1024 + hw0 + tx] = v;
    tile[c][tx] = v;
  }
  __syncthreads();
  #pragma unroll
  for (int r = 0; r < 4; r++) {
    int hw = ty + 8 * r;
    float v = tile[tx][hw];
    out32T[(hw0 + hw) * 512 + c0 + tx] = v;
    sigT[(hw0 + hw) * 512 + c0 + tx] = 1.0f / (1.0f + __expf(-v));
  }
}

// --- K3: merged mid kernel ---
// blocks 0..511   : fused separable gaussian pooling for channel c -> cat first half
// blocks 512..767 : CSA, one wave per location (4 waves/block)     -> cat second half
__global__ void k_gausscsa(const float* __restrict__ out32, const float* __restrict__ gn,
                           const float* __restrict__ sigT, const float* __restrict__ out32T,
                           float* __restrict__ catg) {
  if (blockIdx.x < 512) {
    __shared__ float row[32 * 33];  // [x][y] padded
    __shared__ float g[1024];
    __shared__ float tt[32 * 33];   // [k][x] padded
    int c = blockIdx.x;
    int tid = threadIdx.x;
    for (int idx = tid; idx < 1024; idx += 256) {
      row[(idx >> 5) * 33 + (idx & 31)] = out32[c * 1024 + idx];
      g[idx] = gn[idx];
    }
    __syncthreads();
    // pass 1 (over y): tt[k][x] = sum_y gn[k,y]*row[x,y]
    for (int idx = tid; idx < 1024; idx += 256) {
      int k = idx >> 5, xx = idx & 31;
      float s = 0.0f;
      #pragma unroll
      for (int y = 0; y < 32; y++) s += g[k * 32 + y] * row[xx * 33 + y];
      tt[k * 33 + xx] = s;
    }
    __syncthreads();
    // pass 2 (over x): cat[p*512+c] = sum_x gn[i,x]*tt[k][x],  p=i*32+k
    for (int p = tid; p < 1024; p += 256) {
      int i = p >> 5, k = p & 31;
      float s = 0.0f;
      #pragma unroll
      for (int x = 0; x < 32; x++) s += g[i * 32 + x] * tt[k * 33 + x];
      catg[p * 512 + c] = s;  // scattered store (1024*512 dwords total, L2-absorbed)
    }
  } else {
    // CSA: wave wv handles location p entirely in-wave (no block syncs)
    int wv = threadIdx.x >> 6;
    int lane = threadIdx.x & 63;
    int p = (blockIdx.x - 512) * 4 + wv;
    int h = p >> 5, w = p & 31;
    int c0 = lane * 8;
    float4 ce0 = *(const float4*)&sigT[p * 512 + c0];
    float4 ce1 = *(const float4*)&sigT[p * 512 + c0 + 4];
    int qoff[9];
    float s[9];
    #pragma unroll
    for (int dd = 0; dd < 9; dd++) {
      int hh = h + dd / 3 - 1, ww = w + (dd % 3) - 1;
      bool v = (hh >= 0) && (hh < 32) && (ww >= 0) && (ww < 32);
      qoff[dd] = v ? (hh * 32 + ww) * 512 : -1;
      float a = 0.0f;
      if (v) {
        float4 n0 = *(const float4*)&sigT[qoff[dd] + c0];
        float4 n1 = *(const float4*)&sigT[qoff[dd] + c0 + 4];
        a = ce0.x * n0.x + ce0.y * n0.y + ce0.z * n0.z + ce0.w * n0.w
          + ce1.x * n1.x + ce1.y * n1.y + ce1.z * n1.z + ce1.w * n1.w;
      }
      #pragma unroll
      for (int off = 32; off >= 1; off >>= 1) a += __shfl_xor(a, off);
      s[dd] = a;  // every lane holds the full 512-dot after butterfly
    }
    float mx = -1e30f;
    #pragma unroll
    for (int dd = 0; dd < 9; dd++) { s[dd] *= (1.0f / 512.0f); mx = fmaxf(mx, s[dd]); }
    float tot = 0.0f;
    #pragma unroll
    for (int dd = 0; dd < 9; dd++) { s[dd] = __expf(s[dd] - mx); tot += s[dd]; }
    float inv = 1.0f / tot;
    float4 o0 = make_float4(0, 0, 0, 0), o1 = make_float4(0, 0, 0, 0);
    #pragma unroll
    for (int dd = 0; dd < 9; dd++) {
      if (qoff[dd] >= 0) {
        float att = s[dd] * inv;
        float4 r0 = *(const float4*)&out32T[qoff[dd] + c0];
        float4 r1 = *(const float4*)&out32T[qoff[dd] + c0 + 4];
        o0.x += att * r0.x; o0.y += att * r0.y; o0.z += att * r0.z; o0.w += att * r0.w;
        o1.x += att * r1.x; o1.y += att * r1.y; o1.z += att * r1.z; o1.w += att * r1.w;
      }
    }
    *(float4*)&catg[524288 + p * 512 + c0] = o0;
    *(float4*)&catg[524288 + p * 512 + c0 + 4] = o1;
  }
}

// --- K4: fp32 GEMM y[512][1024] = w_down[512][1024] * cat[1024][1024] ---
// 64x64 tile, 4x4 per thread, K-split 8 (blockIdx.z), partials summed in k_inorm.
__global__ void k_gemm(const float* __restrict__ A, const float* __restrict__ B,
                       float* __restrict__ Cp) {
  __shared__ __align__(16) float As[32][68];  // [k][m], stride 68: b128-aligned reads
  __shared__ __align__(16) float Bs[32][64];  // [k][n]
  int tid = threadIdx.x;
  int tx = tid & 15;        // n-quad
  int ty = tid >> 4;        // m-quad (0..15)
  int bn = blockIdx.x * 64;
  int bm = blockIdx.y * 64;
  int zK = blockIdx.z * 128;
  int a_m = tid >> 5;       // 0..7
  int a_k = tid & 31;
  int b_row = tid >> 4;     // 0..15
  int b_q = tid & 15;
  float acc[4][4] = {};
  for (int k0 = 0; k0 < 128; k0 += 32) {
    #pragma unroll
    for (int r = 0; r < 8; r++) {
      As[a_k][a_m + 8 * r] = A[(bm + a_m + 8 * r) * 1024 + zK + k0 + a_k];
    }
    #pragma unroll
    for (int r = 0; r < 2; r++) {
      float4 v = *(const float4*)&B[(zK + k0 + b_row + 16 * r) * 1024 + bn + b_q * 4];
      *(float4*)&Bs[b_row + 16 * r][b_q * 4] = v;
    }
    __syncthreads();
    #pragma unroll
    for (int k = 0; k < 32; k++) {
      float4 av = *(const float4*)&As[k][ty * 4];
      float4 bv = *(const float4*)&Bs[k][tx * 4];
      acc[0][0] += av.x * bv.x; acc[0][1] += av.x * bv.y; acc[0][2] += av.x * bv.z; acc[0][3] += av.x * bv.w;
      acc[1][0] += av.y * bv.x; acc[1][1] += av.y * bv.y; acc[1][2] += av.y * bv.z; acc[1][3] += av.y * bv.w;
      acc[2][0] += av.z * bv.x; acc[2][1] += av.z * bv.y; acc[2][2] += av.z * bv.z; acc[2][3] += av.z * bv.w;
      acc[3][0] += av.w * bv.x; acc[3][1] += av.w * bv.y; acc[3][2] += av.w * bv.z; acc[3][3] += av.w * bv.w;
    }
    __syncthreads();
  }
  float* Cz = Cp + blockIdx.z * 524288;
  #pragma unroll
  for (int i = 0; i < 4; i++) {
    float4 v = make_float4(acc[i][0], acc[i][1], acc[i][2], acc[i][3]);
    *(float4*)&Cz[(bm + ty * 4 + i) * 1024 + bn + tx * 4] = v;
  }
}

// --- K5: sum 8 K-split partials + instance norm (biased var) + LeakyReLU(0.2) ---
__global__ void k_inorm(const float* __restrict__ yp, float* __restrict__ out) {
  __shared__ float sm4[4];
  __shared__ float vrow[1024];
  int o = blockIdx.x;
  const float* r0 = yp + o * 1024;
  float s = 0.0f, q = 0.0f;
  for (int i = threadIdx.x; i < 1024; i += 256) {
    float v = 0.0f;
    #pragma unroll
    for (int j = 0; j < 8; j++) v += r0[i + j * 524288];
    vrow[i] = v;
    s += v; q += v * v;
  }
  float ts = block_reduce_256(s, sm4);
  float tq = block_reduce_256(q, sm4);
  float mean = ts * (1.0f / 1024.0f);
  float var = tq * (1.0f / 1024.0f) - mean * mean;
  float inv = rsqrtf(var + 1e-5f);
  for (int i = threadIdx.x; i < 1024; i += 256) {
    float v = (vrow[i] - mean) * inv;
    out[o * 1024 + i] = v >= 0.0f ? v : 0.2f * v;
  }
}

extern "C" void kernel_launch(void* const* d_in, const int* in_sizes, int n_in,
                              void* d_out, int out_size, void* d_ws, size_t ws_size,
                              hipStream_t stream) {
  const float* x      = (const float*)d_in[0];  // (1,512,32,32)
  const float* w_se1  = (const float*)d_in[1];  // (32,512)
  const float* w_se2  = (const float*)d_in[2];  // (512,32)
  const float* w_down = (const float*)d_in[3];  // (512,1024,1,1)
  float* out = (float*)d_out;                   // (1,512,32,32)

  float* ws = (float*)d_ws;
  float* gn     = ws;                  // 1024
  float* smean  = ws + 1024;           // 512
  float* out32  = ws + 2048;           // 524288   (c-major)
  float* out32T = out32 + 524288;      // 524288   (hw-major)
  float* sigT   = out32T + 524288;     // 524288   (hw-major)
  float* cat    = sigT + 524288;       // 1048576  GEMM B matrix (gus | csa)
  float* ypart  = cat + 1048576;       // 8 x 524288 split-K partials (~27 MB total ws)

  k_mean_gn<<<513, 256, 0, stream>>>(x, smean, gn);
  k_apply<<<dim3(32, 16), 256, 0, stream>>>(x, smean, w_se1, w_se2, out32, out32T, sigT);
  k_gausscsa<<<768, 256, 0, stream>>>(out32, gn, sigT, out32T, cat);
  k_gemm<<<dim3(16, 8, 8), 256, 0, stream>>>(w_down, cat, ypart);
  k_inorm<<<512, 256, 0, stream>>>(ypart, out);
}

// Round 4
// 111.667 us; speedup vs baseline: 1.6039x; 1.0492x over previous
//
#include <hip/hip_runtime.h>

// Problem constants: H=W=32, HW=1024, C=512, 2C=1024, sigma=1.5 -> 2*v^2=4.5

typedef short short8 __attribute__((ext_vector_type(8)));
typedef short short4v __attribute__((ext_vector_type(4)));
typedef float floatx4 __attribute__((ext_vector_type(4)));

__device__ __forceinline__ unsigned short f2bf(float x) {
  union { float f; unsigned u; } v; v.f = x;
  unsigned u = v.u;
  u = (u + 0x7fffu + ((u >> 16) & 1u)) >> 16;   // RNE
  return (unsigned short)u;
}

__device__ __forceinline__ float block_reduce_256(float v, float* sm4) {
  #pragma unroll
  for (int off = 32; off >= 1; off >>= 1) v += __shfl_down(v, off);
  __syncthreads();
  if ((threadIdx.x & 63) == 0) sm4[threadIdx.x >> 6] = v;
  __syncthreads();
  return sm4[0] + sm4[1] + sm4[2] + sm4[3];
}

// --- K1: blocks 0..511 per-channel mean; block 512 gaussian weights; 513..768 w_down->bf16 ---
__global__ void k_mean_gn(const float* __restrict__ x, float* __restrict__ smean,
                          float* __restrict__ gn, const float* __restrict__ wdn,
                          unsigned short* __restrict__ Abf) {
  if (blockIdx.x > 512) {
    int base = (blockIdx.x - 513) * 2048 + threadIdx.x * 8;
    float4 a = *(const float4*)&wdn[base];
    float4 b = *(const float4*)&wdn[base + 4];
    short8 s;
    s[0] = (short)f2bf(a.x); s[1] = (short)f2bf(a.y); s[2] = (short)f2bf(a.z); s[3] = (short)f2bf(a.w);
    s[4] = (short)f2bf(b.x); s[5] = (short)f2bf(b.y); s[6] = (short)f2bf(b.z); s[7] = (short)f2bf(b.w);
    *(short8*)&Abf[base] = s;
    return;
  }
  if (blockIdx.x == 512) {
    int tid = threadIdx.x;
    int a = tid >> 3;            // 0..31 row
    int b0 = (tid & 7) * 4;      // 4 cols per thread
    float e[4];
    float s = 0.0f;
    #pragma unroll
    for (int q = 0; q < 4; q++) {
      float d = (float)(a - (b0 + q));
      e[q] = __expf(d * d * (-1.0f / 4.5f));
      s += e[q];
    }
    s += __shfl_xor(s, 1, 8);
    s += __shfl_xor(s, 2, 8);
    s += __shfl_xor(s, 4, 8);
    float inv = 1.0f / s;
    #pragma unroll
    for (int q = 0; q < 4; q++) gn[a * 32 + b0 + q] = e[q] * inv;
    return;
  }
  __shared__ float sm4[4];
  int c = blockIdx.x;
  const float* row = x + c * 1024;
  float s = 0.0f;
  for (int i = threadIdx.x; i < 1024; i += 256) s += row[i];
  float t = block_reduce_256(s, sm4);
  if (threadIdx.x == 0) smean[c] = t * (1.0f / 1024.0f);
}

// --- K2: SE (redundant per block) + scale + transposes (+ V[y][x][c] swizzled copy) ---
__global__ void k_apply(const float* __restrict__ x, const float* __restrict__ smean,
                        const float* __restrict__ w1, const float* __restrict__ w2,
                        float* __restrict__ out32T, float* __restrict__ sigT,
                        float* __restrict__ V) {
  __shared__ float sm[512];
  __shared__ float s1[32];
  __shared__ float sc[32];
  __shared__ float tile[32][33];
  int tid = threadIdx.x;
  for (int i = tid; i < 512; i += 256) sm[i] = smean[i];
  __syncthreads();
  int j = tid >> 3, l8 = tid & 7;
  float a = 0.0f;
  for (int cc = l8; cc < 512; cc += 8) a += sm[cc] * w1[j * 512 + cc];
  a += __shfl_down(a, 4, 8);
  a += __shfl_down(a, 2, 8);
  a += __shfl_down(a, 1, 8);
  if (l8 == 0) s1[j] = fmaxf(a, 0.0f);
  __syncthreads();
  int c0 = blockIdx.y * 32, hw0 = blockIdx.x * 32;
  if (tid < 32) {
    float b = 0.0f;
    #pragma unroll
    for (int jj = 0; jj < 32; jj++) b += s1[jj] * w2[(c0 + tid) * 32 + jj];
    sc[tid] = 1.0f / (1.0f + __expf(-b));
  }
  __syncthreads();
  int tx = tid & 31, ty = tid >> 5;  // ty 0..7
  #pragma unroll
  for (int r = 0; r < 4; r++) {
    int c = ty + 8 * r;
    float v = x[(c0 + c) * 1024 + hw0 + tx] * sc[c];
    tile[c][tx] = v;
  }
  __syncthreads();
  #pragma unroll
  for (int r = 0; r < 4; r++) {
    int hw = hw0 + ty + 8 * r;
    float v = tile[tx][ty + 8 * r];
    out32T[hw * 512 + c0 + tx] = v;
    sigT[hw * 512 + c0 + tx] = 1.0f / (1.0f + __expf(-v));
    int hwsw = ((hw & 31) << 5) | (hw >> 5);       // V[(y*32+x)][c] = out32[c][x*32+y]
    V[hwsw * 512 + c0 + tx] = v;
  }
}

// --- K3: blocks 0..511 gauss pass1 T1[(k,x)][c] = sum_y g[k][y] V[(y,x)][c];
//         blocks 512..767 CSA (wave per location) -> catT bf16 right half ---
__global__ void k_g1csa(const float* __restrict__ V, const float* __restrict__ gn,
                        const float* __restrict__ sigT, const float* __restrict__ out32T,
                        float* __restrict__ T1, unsigned short* __restrict__ catT) {
  if (blockIdx.x < 512) {
    __shared__ float g[1024];
    int tid = threadIdx.x;
    for (int i = tid; i < 1024; i += 256) g[i] = gn[i];
    __syncthreads();
    int t = blockIdx.x * 256 + tid;
    int c = t & 511;
    int xk = t >> 9;            // 0..255
    int xx = xk & 31, kg = xk >> 5;   // k0 = kg*4
    const float* vp = V + xx * 512 + c;
    const float* g0 = g + kg * 4 * 32;
    float s0 = 0, s1 = 0, s2 = 0, s3 = 0;
    #pragma unroll 8
    for (int y = 0; y < 32; y++) {
      float vv = vp[y * 16384];
      s0 += g0[y] * vv;
      s1 += g0[32 + y] * vv;
      s2 += g0[64 + y] * vv;
      s3 += g0[96 + y] * vv;
    }
    int ko = kg * 4 * 32 + xx;   // (k*32 + x)
    T1[ko * 512 + c] = s0;
    T1[(ko + 32) * 512 + c] = s1;
    T1[(ko + 64) * 512 + c] = s2;
    T1[(ko + 96) * 512 + c] = s3;
  } else {
    int wv = threadIdx.x >> 6;
    int lane = threadIdx.x & 63;
    int p = (blockIdx.x - 512) * 4 + wv;
    int h = p >> 5, w = p & 31;
    int c0 = lane * 8;
    float4 ce0 = *(const float4*)&sigT[p * 512 + c0];
    float4 ce1 = *(const float4*)&sigT[p * 512 + c0 + 4];
    int qoff[9];
    float s[9];
    #pragma unroll
    for (int dd = 0; dd < 9; dd++) {
      int hh = h + dd / 3 - 1, ww = w + (dd % 3) - 1;
      bool v = (hh >= 0) && (hh < 32) && (ww >= 0) && (ww < 32);
      qoff[dd] = v ? (hh * 32 + ww) * 512 : -1;
      float a = 0.0f;
      if (v) {
        float4 n0 = *(const float4*)&sigT[qoff[dd] + c0];
        float4 n1 = *(const float4*)&sigT[qoff[dd] + c0 + 4];
        a = ce0.x * n0.x + ce0.y * n0.y + ce0.z * n0.z + ce0.w * n0.w
          + ce1.x * n1.x + ce1.y * n1.y + ce1.z * n1.z + ce1.w * n1.w;
      }
      #pragma unroll
      for (int off = 32; off >= 1; off >>= 1) a += __shfl_xor(a, off);
      s[dd] = a;
    }
    float mx = -1e30f;
    #pragma unroll
    for (int dd = 0; dd < 9; dd++) { s[dd] *= (1.0f / 512.0f); mx = fmaxf(mx, s[dd]); }
    float tot = 0.0f;
    #pragma unroll
    for (int dd = 0; dd < 9; dd++) { s[dd] = __expf(s[dd] - mx); tot += s[dd]; }
    float inv = 1.0f / tot;
    float o[8] = {0, 0, 0, 0, 0, 0, 0, 0};
    #pragma unroll
    for (int dd = 0; dd < 9; dd++) {
      if (qoff[dd] >= 0) {
        float att = s[dd] * inv;
        float4 r0 = *(const float4*)&out32T[qoff[dd] + c0];
        float4 r1 = *(const float4*)&out32T[qoff[dd] + c0 + 4];
        o[0] += att * r0.x; o[1] += att * r0.y; o[2] += att * r0.z; o[3] += att * r0.w;
        o[4] += att * r1.x; o[5] += att * r1.y; o[6] += att * r1.z; o[7] += att * r1.w;
      }
    }
    // flat index f = 524288 + p*512 + c  ->  catT[n = (p&1)*512+c][k = 512 + (p>>1)]
    int kcol = 512 + (p >> 1);
    int nbase = (p & 1) * 512 + c0;
    #pragma unroll
    for (int q = 0; q < 8; q++) catT[(nbase + q) * 1024 + kcol] = f2bf(o[q]);
  }
}

// --- K4: gauss pass2: S[(i,k)][c] = sum_x g[i][x] T1[(k,x)][c] -> catT bf16 left half ---
__global__ void k_g2(const float* __restrict__ T1, const float* __restrict__ gn,
                     unsigned short* __restrict__ catT) {
  __shared__ float g[1024];
  int tid = threadIdx.x;
  for (int i = tid; i < 1024; i += 256) g[i] = gn[i];
  __syncthreads();
  int t = blockIdx.x * 256 + tid;
  int c = t & 511;
  int rest = t >> 9;           // 0..255
  int i = rest >> 3;           // 0..31
  int sub = rest & 7;
  int par = sub & 1, kq = sub >> 1;   // k_j = kq*8 + par + 2j
  const float* tp = T1 + c;
  const float* gi = g + i * 32;
  float s0 = 0, s1 = 0, s2 = 0, s3 = 0;
  int kb = kq * 8 + par;
  #pragma unroll 8
  for (int xx = 0; xx < 32; xx++) {
    float gv = gi[xx];
    s0 += gv * tp[((kb + 0) * 32 + xx) * 512];
    s1 += gv * tp[((kb + 2) * 32 + xx) * 512];
    s2 += gv * tp[((kb + 4) * 32 + xx) * 512];
    s3 += gv * tp[((kb + 6) * 32 + xx) * 512];
  }
  // flat f = p*512+c, p=i*32+k -> catT[n=(par*512+c)][kcol=i*16+kq*4+j], j=0..3
  short4v o;
  o[0] = (short)f2bf(s0); o[1] = (short)f2bf(s1); o[2] = (short)f2bf(s2); o[3] = (short)f2bf(s3);
  *(short4v*)&catT[(par * 512 + c) * 1024 + i * 16 + kq * 4] = o;
}

// --- K5: bf16 MFMA GEMM y[512][1024] = Abf[512][1024] x catT^T; split-K 2 ---
// Wave tile M16xN32; fragments loaded directly from global (L2-resident).
__global__ void k_gemm(const unsigned short* __restrict__ Abf,
                       const unsigned short* __restrict__ Bbf,
                       float* __restrict__ yp) {
  int wv = threadIdx.x >> 6, lane = threadIdx.x & 63;
  int w0 = blockIdx.x;             // 0..511
  int m = w0 >> 4;                 // 0..31
  int n0 = (w0 & 15) * 64;
  int nn = n0 + (wv & 1) * 32;
  int kz = wv >> 1;                // split-K half
  int l16 = lane & 15, quad = lane >> 4;
  const short8* ap  = (const short8*)(Abf + (m * 16 + l16) * 1024 + kz * 512 + quad * 8);
  const short8* bp0 = (const short8*)(Bbf + (nn + l16) * 1024 + kz * 512 + quad * 8);
  const short8* bp1 = (const short8*)(Bbf + (nn + 16 + l16) * 1024 + kz * 512 + quad * 8);
  floatx4 acc0 = {0.f, 0.f, 0.f, 0.f}, acc1 = {0.f, 0.f, 0.f, 0.f};
  #pragma unroll 4
  for (int kk = 0; kk < 16; kk++) {
    short8 a  = ap[kk * 4];        // 32 shorts (=64B) per k-step
    short8 b0 = bp0[kk * 4];
    short8 b1 = bp1[kk * 4];
    acc0 = __builtin_amdgcn_mfma_f32_16x16x32_bf16(a, b0, acc0, 0, 0, 0);
    acc1 = __builtin_amdgcn_mfma_f32_16x16x32_bf16(a, b1, acc1, 0, 0, 0);
  }
  // C/D layout: col = lane&15, row = quad*4 + r
  float* yo = yp + kz * 524288 + (m * 16 + quad * 4) * 1024 + l16;
  #pragma unroll
  for (int r = 0; r < 4; r++) {
    yo[r * 1024 + nn] = acc0[r];
    yo[r * 1024 + nn + 16] = acc1[r];
  }
}

// --- K6: sum 2 K-split partials + instance norm (biased var) + LeakyReLU(0.2) ---
__global__ void k_inorm(const float* __restrict__ yp, float* __restrict__ out) {
  __shared__ float sm4[4];
  __shared__ float vrow[1024];
  int o = blockIdx.x;
  const float* r0 = yp + o * 1024;
  float s = 0.0f, q = 0.0f;
  for (int i = threadIdx.x; i < 1024; i += 256) {
    float v = r0[i] + r0[i + 524288];
    vrow[i] = v;
    s += v; q += v * v;
  }
  float ts = block_reduce_256(s, sm4);
  float tq = block_reduce_256(q, sm4);
  float mean = ts * (1.0f / 1024.0f);
  float var = tq * (1.0f / 1024.0f) - mean * mean;
  float inv = rsqrtf(var + 1e-5f);
  for (int i = threadIdx.x; i < 1024; i += 256) {
    float v = (vrow[i] - mean) * inv;
    out[o * 1024 + i] = v >= 0.0f ? v : 0.2f * v;
  }
}

extern "C" void kernel_launch(void* const* d_in, const int* in_sizes, int n_in,
                              void* d_out, int out_size, void* d_ws, size_t ws_size,
                              hipStream_t stream) {
  const float* x      = (const float*)d_in[0];  // (1,512,32,32)
  const float* w_se1  = (const float*)d_in[1];  // (32,512)
  const float* w_se2  = (const float*)d_in[2];  // (512,32)
  const float* w_down = (const float*)d_in[3];  // (512,1024,1,1)
  float* out = (float*)d_out;                   // (1,512,32,32)

  float* ws = (float*)d_ws;
  float* gn     = ws;                        // 1024
  float* smean  = ws + 1024;                 // 512
  float* out32T = ws + 2048;                 // 524288  [hw][c]
  float* sigT   = out32T + 524288;           // 524288  [hw][c]
  float* V      = sigT + 524288;             // 524288  [(y,x)][c]
  float* T1     = V + 524288;                // 524288  [(k,x)][c]
  unsigned short* catT = (unsigned short*)(T1 + 524288);   // 1024x1024 bf16 [n][k]
  unsigned short* Abf  = (unsigned short*)(T1 + 1048576);  // 512x1024 bf16
  float* yp     = T1 + 1310720;              // 2 x 524288 split-K partials

  k_mean_gn<<<769, 256, 0, stream>>>(x, smean, gn, w_down, Abf);
  k_apply<<<dim3(32, 16), 256, 0, stream>>>(x, smean, w_se1, w_se2, out32T, sigT, V);
  k_g1csa<<<768, 256, 0, stream>>>(V, gn, sigT, out32T, T1, catT);
  k_g2<<<512, 256, 0, stream>>>(T1, gn, catT);
  k_gemm<<<512, 256, 0, stream>>>(Abf, catT, yp);
  k_inorm<<<512, 256, 0, stream>>>(yp, out);
}